// Round 3
// baseline (282.473 us; speedup 1.0000x reference)
//
#include <hip/hip_runtime.h>

// SSIM loss — barrier-free streaming separable conv, v3.
// Grid: 4 x 32 x 48 blocks of 128 threads = 2 INDEPENDENT waves (no barriers).
// Each wave owns a 64-col x 16-row strip; each lane owns ONE output column.
// Per input row (26 steps incl 10 halo rows):
//   read 11-pair window from row buffer (ds_read_b64, stride-2 words =
//   conflict-free; pairs merge to ds_read2_b64),
//   stage NEXT row into the OTHER buffer (true double buffer: write latency
//   hidden behind a full compute phase; parity u&1 is static via 12-step
//   unrolled chunks -> distinct __shared__ arrays, no alias stalls),
//   horizontal 11-tap conv of {a,b}->{h1,h2},{h11,h22},h12 via packed f32,
//   push into 12-slot register ring (slot = s mod 12, static),
//   vertical 11-tap conv from ring + SSIM once s>=10.
// One float atomicAdd per wave; finalize kernel does 1 - sum/N.

typedef float v2f __attribute__((ext_vector_type(2)));
typedef float v4f __attribute__((ext_vector_type(4)));

#define IMG    512
#define WCOLS  64           // output cols per wave (1 per lane)
#define SROWS  16           // output rows per strip
#define NSTEPS 26           // SROWS + 10
#define BUFW   160          // (64 + 16 halo) cols * 2 images, interleaved {a,b}
#define NPIX   (16.0f * 3.0f * 512.0f * 512.0f)

__device__ __forceinline__ float clamp01(float x) {
    // fmaxf(NaN,0) -> 0: nan_to_num + clip(0,1)
    return fminf(fmaxf(x, 0.0f), 1.0f);
}

__device__ __forceinline__ float ssim_px(v2f mu, v2f e, float e12) {
    const float C1 = 1.01e-4f;   // 0.01^2 + 1e-6
    const float C2 = 9.01e-4f;   // 0.03^2 + 1e-6
    v2f musq = mu * mu;                       // {mu1^2, mu2^2}
    float mu12 = mu.x * mu.y;
    v2f sig = e - musq;                       // {sig1, sig2}
    v2f lo = {1e-6f, 1e-6f};
    v2f hi = {1e6f, 1e6f};
    sig = __builtin_elementwise_max(sig, lo);
    sig = __builtin_elementwise_min(sig, hi);
    float s12 = e12 - mu12;
    float num = fmaf(2.f, mu12, C1) * fmaf(2.f, s12, C2);
    float den = (musq.x + musq.y + C1) * (sig.x + sig.y + C2);  // >= C1*C2 > 0
    return num * __builtin_amdgcn_rcpf(den);
}

__global__ __launch_bounds__(128, 4)
void ssim_stream_kernel(const float* __restrict__ imgA,
                        const float* __restrict__ imgB,
                        float* __restrict__ accum)
{
    // Gaussian 11-tap, sigma=1.5, normalized (verified exact in R1/R2)
    constexpr float GW[11] = {
        0.00102838f, 0.00759880f, 0.03600077f, 0.10936070f, 0.21300554f,
        0.26601173f,
        0.21300554f, 0.10936070f, 0.03600077f, 0.00759880f, 0.00102838f
    };

    // per-wave private row buffers, interleaved {a,b} pairs, double-buffered
    __shared__ __attribute__((aligned(16))) float sb0[2][BUFW];
    __shared__ __attribute__((aligned(16))) float sb1[2][BUFW];

    const int tid  = threadIdx.x;
    const int wv   = tid >> 6;
    const int lane = tid & 63;
    float* b0 = sb0[wv];
    float* b1 = sb1[wv];

    const int C0 = blockIdx.x * (2 * WCOLS) + wv * WCOLS;
    const int R0 = blockIdx.y * SROWS;
    const size_t pOff = (size_t)blockIdx.z * (size_t)(IMG * IMG);
    const float* pA = imgA + pOff;
    const float* pB = imgB + pOff;

    // staging: lanes 0..19 each own one 4-col quad of BOTH images.
    // quad q=lane covers cols C0-8+4q .. +3; LDS words 8q..8q+7 (interleaved).
    const bool stg  = lane < 20;
    const int col0  = C0 - 8 + 4 * lane;
    const bool okc  = stg && (col0 >= 0) && (col0 <= IMG - 4);
    const int wbase = 8 * lane;

    // 12-slot register ring of horizontal results (slot = s mod 12, static)
    v2f rA[12], rB[12];
    float rC[12];
#pragma unroll
    for (int i = 0; i < 12; ++i) { rA[i] = 0; rB[i] = 0; rC[i] = 0; }

    float4 na = make_float4(0, 0, 0, 0), nb = na;   // prefetch regs

    auto fetch = [&](int s, float4& qa, float4& qb) {
        qa = make_float4(0, 0, 0, 0);
        qb = make_float4(0, 0, 0, 0);
        const int ir = R0 - 5 + s;
        if (okc && (unsigned)ir < (unsigned)IMG && s < NSTEPS) {
            qa = *(const float4*)(pA + (size_t)ir * IMG + col0);
            qb = *(const float4*)(pB + (size_t)ir * IMG + col0);
        }
    };
    auto stage = [&](float* dst, const float4& qa, const float4& qb) {
        if (stg) {
            v4f w0 = {clamp01(qa.x), clamp01(qb.x), clamp01(qa.y), clamp01(qb.y)};
            v4f w1 = {clamp01(qa.z), clamp01(qb.z), clamp01(qa.w), clamp01(qb.w)};
            *(v4f*)(dst + wbase)     = w0;
            *(v4f*)(dst + wbase + 4) = w1;
        }
    };

    float lsum = 0.f;

    // step body; u is a compile-time constant under full unroll
    auto body = [&](int s, int u, bool dovert) {
        float* src = (u & 1) ? b1 : b0;
        float* dst = (u & 1) ? b0 : b1;

        // 1. window reads FIRST (stride-2-word b64s, conflict-free).
        //    output col X = C0+lane; window pairs xr = lane+3 .. lane+13.
        v2f w[11];
        const v2f* wp = (const v2f*)src + (lane + 3);
#pragma unroll
        for (int j = 0; j < 11; ++j) w[j] = wp[j];

        // 2. stage prefetched row s+1 into the other buffer (writes are
        //    younger than the reads above; consumed only next step).
        stage(dst, na, nb);

        // 3. prefetch row s+2 from global (slack = one full step)
        fetch(s + 2, na, nb);

        // 4. horizontal conv (packed f32)
        v2f hA = 0, hB = 0;
        float hC = 0;
#pragma unroll
        for (int j = 0; j < 11; ++j) {
            v2f wj = w[j];
            v2f g  = GW[j] * wj;            // {g*a, g*b}
            hA += g;                        // {h1, h2}
            hB += g * wj;                   // {h11, h22}
            hC  = fmaf(g.x, wj.y, hC);      // h12
        }
        rA[u] = hA; rB[u] = hB; rC[u] = hC;

        // 5. vertical conv from ring + SSIM (output row R0+s-10)
        if (dovert) {
            v2f vA = 0, vB = 0;
            float vC = 0;
#pragma unroll
            for (int i = 0; i < 11; ++i) {
                const int sl = (u + 2 + i) % 12;   // slot of step s-10+i (static)
                const float gi = GW[i];
                vA += gi * rA[sl];
                vB += gi * rB[sl];
                vC  = fmaf(gi, rC[sl], vC);
            }
            lsum += ssim_px(vA, vB, vC);
        }
    };

    // prologue: stage row for step 0 into b0, prefetch row for step 1
    {
        float4 qa, qb;
        fetch(0, qa, qb);
        stage(b0, qa, qb);
        fetch(1, na, nb);
    }

    // 2 chunks of 12 steps (s = 0..23), then static tail (s = 24, 25)
#pragma unroll 1
    for (int ch = 0; ch < 24; ch += 12) {
#pragma unroll
        for (int u = 0; u < 12; ++u) {
            body(ch + u, u, (ch + u) >= 10);
        }
    }
    body(24, 0, true);
    body(25, 1, true);

    // wave64 reduce, one atomic per wave
#pragma unroll
    for (int off = 32; off >= 1; off >>= 1)
        lsum += __shfl_down(lsum, off, 64);
    if (lane == 0) atomicAdd(accum, lsum);
}

__global__ void ssim_finalize_kernel(const float* __restrict__ accum,
                                     float* __restrict__ out) {
    out[0] = 1.0f - accum[0] * (1.0f / NPIX);
}

extern "C" void kernel_launch(void* const* d_in, const int* in_sizes, int n_in,
                              void* d_out, int out_size, void* d_ws, size_t ws_size,
                              hipStream_t stream) {
    const float* img1 = (const float*)d_in[0];
    const float* img2 = (const float*)d_in[1];
    float* out = (float*)d_out;
    float* ws  = (float*)d_ws;

    hipMemsetAsync(ws, 0, sizeof(float), stream);   // ws re-poisoned every call

    dim3 grid(IMG / (2 * WCOLS), IMG / SROWS, 48);  // 4 x 32 x 48 = 6144 blocks
    ssim_stream_kernel<<<grid, 128, 0, stream>>>(img1, img2, ws);
    ssim_finalize_kernel<<<1, 1, 0, stream>>>(ws, out);
}